// Round 6
// baseline (83.973 us; speedup 1.0000x reference)
//
#include <hip/hip_runtime.h>
#include <stdint.h>

#define B_   8
#define S_   2048
#define HID_ 512
#define M_   (B_ * S_)   // 16384
#define AW_  5

typedef __attribute__((ext_vector_type(8))) short bf16x8;
typedef __attribute__((ext_vector_type(4))) float f32x4;
typedef unsigned short u16;

__device__ __forceinline__ u16 f2bf(float f) {
    uint32_t u = __builtin_bit_cast(uint32_t, f);
    u += 0x7FFFu + ((u >> 16) & 1u);   // RNE
    return (u16)(u >> 16);
}
__device__ __forceinline__ float bf2f(u16 h) {
    uint32_t u = ((uint32_t)h) << 16;
    return __builtin_bit_cast(float, u);
}

// async global->LDS, 16B/lane (dest = wave-uniform base + lane*16, linear)
__device__ __forceinline__ void gload16(const void* g, void* l) {
    __builtin_amdgcn_global_load_lds(
        (const __attribute__((address_space(1))) void*)(uintptr_t)g,
        (__attribute__((address_space(3))) void*)(uint32_t)(uintptr_t)l,
        16, 0, 0);
}

#define WAITV(n)  asm volatile("s_waitcnt vmcnt(" #n ")" ::: "memory")
#define WAITLG0() asm volatile("s_waitcnt lgkmcnt(0)" ::: "memory")

// ---------------------------------------------------------------------------
// prep: W1^T, Wv^T always; W2^T if do_w2. 768 blocks (256 per weight).
// ---------------------------------------------------------------------------
__global__ __launch_bounds__(256) void prep_w(const float* __restrict__ W1,
                                              const float* __restrict__ Wv,
                                              const float* __restrict__ W2,
                                              u16* __restrict__ W1t,
                                              u16* __restrict__ Wvt,
                                              u16* __restrict__ W2t,
                                              int do_w2) {
    const int wsel = blockIdx.x >> 8;
    if (wsel == 2 && !do_w2) return;
    const float* src = wsel == 0 ? W1 : (wsel == 1 ? Wv : W2);
    u16* dst = wsel == 0 ? W1t : (wsel == 1 ? Wvt : W2t);
    const int t  = blockIdx.x & 255;
    const int n0 = (t & 15) * 32, k0 = (t >> 4) * 32;
    __shared__ float tile[32][33];
    const int tr = threadIdx.x >> 5, tc = threadIdx.x & 31;
#pragma unroll
    for (int p = 0; p < 4; ++p)
        tile[tr + p * 8][tc] = src[(long)(k0 + tr + p * 8) * HID_ + n0 + tc];
    __syncthreads();
#pragma unroll
    for (int p = 0; p < 4; ++p)
        dst[(long)(n0 + tr + p * 8) * HID_ + k0 + tc] = f2bf(tile[tc][tr + p * 8]);
}

// ---------------------------------------------------------------------------
// late W2 transpose (fallback when ws is small)
// ---------------------------------------------------------------------------
__global__ __launch_bounds__(256) void trans_w2(const float* __restrict__ W2,
                                                u16* __restrict__ W2t) {
    __shared__ float tile[32][33];
    const int k0 = blockIdx.y * 32, n0 = blockIdx.x * 32;
    const int tr = threadIdx.x >> 5, tc = threadIdx.x & 31;
#pragma unroll
    for (int p = 0; p < 4; ++p)
        tile[tr + p * 8][tc] = W2[(long)(k0 + tr + p * 8) * HID_ + n0 + tc];
    __syncthreads();
#pragma unroll
    for (int p = 0; p < 4; ++p)
        W2t[(long)(n0 + tr + p * 8) * HID_ + k0 + tc] = f2bf(tile[tc][tr + p * 8]);
}

// ---------------------------------------------------------------------------
// gemm1: h = relu(x @ W1 + b1), A f32 (cvt fused via reg-staging), 128x128
// tile, BK=64, 2-buffer LDS, T2 swizzle, XCD swizzle. (proven R4 body)
// ---------------------------------------------------------------------------
__global__ __launch_bounds__(256, 2) void gemm1_f32a(const float* __restrict__ A,
                                                     const u16* __restrict__ Bt,
                                                     const float* __restrict__ bias,
                                                     u16* __restrict__ C) {
    __shared__ __attribute__((aligned(16))) u16 As[2][128 * 64];
    __shared__ __attribute__((aligned(16))) u16 Bs[2][128 * 64];

    const int tid = threadIdx.x;
    const int bid = blockIdx.x;
    const int swz = (bid & 7) * 64 + (bid >> 3);   // 512 blocks, bijective
    const int  bn   = (swz & 3) * 128;
    const long brow = (long)(swz >> 2) * 128;

    const int w  = tid >> 6;
    const int l  = tid & 63;
    const int wm = (w >> 1) * 64;
    const int wn = (w & 1) * 64;
    const int lr  = l & 15;
    const int lkb = (l >> 4) * 16;
    const int sw  = (lr & 7) << 4;

    const int r0 = tid >> 2;
    const int c0 = (tid & 3) * 16;
    const int r1 = 64 + r0;
    const float* ga0 = A + (brow + r0) * 512 + c0;
    const float* ga1 = A + (brow + r1) * 512 + c0;
    char* lw = (char*)&As[0][0];
    const int wb00 = r0 * 128 + ((c0 * 2 +  0) ^ ((r0 & 7) << 4));
    const int wb01 = r0 * 128 + ((c0 * 2 + 16) ^ ((r0 & 7) << 4));
    const int wb10 = r1 * 128 + ((c0 * 2 +  0) ^ ((r1 & 7) << 4));
    const int wb11 = r1 * 128 + ((c0 * 2 + 16) ^ ((r1 & 7) << 4));

    int pq[4];
    const u16* srcB[4];
#pragma unroll
    for (int q = 0; q < 4; ++q) {
        const int p   = tid * 16 + q * 4096;
        const int row = p >> 7;
        const int cb  = (p & 127) ^ ((row & 7) << 4);
        pq[q]   = p;
        srcB[q] = Bt + (long)(bn + row) * 512 + (cb >> 1);
    }

    f32x4 acc[4][4];
#pragma unroll
    for (int i = 0; i < 4; ++i)
#pragma unroll
        for (int j = 0; j < 4; ++j) {
            f32x4 z = {0.f, 0.f, 0.f, 0.f};
            acc[i][j] = z;
        }

    float4 ra[4], rb[4];

#define LOADA(k0)                                                        \
    {                                                                    \
        _Pragma("unroll") for (int u = 0; u < 4; ++u) {                  \
            ra[u] = *(const float4*)(ga0 + (k0) + u * 4);                \
            rb[u] = *(const float4*)(ga1 + (k0) + u * 4);                \
        }                                                                \
    }
#define CVTWRITE(buf)                                                    \
    {                                                                    \
        union { u16 u[8]; int4 v; } q0, q1, q2, q3;                      \
        q0.u[0]=f2bf(ra[0].x); q0.u[1]=f2bf(ra[0].y); q0.u[2]=f2bf(ra[0].z); q0.u[3]=f2bf(ra[0].w); \
        q0.u[4]=f2bf(ra[1].x); q0.u[5]=f2bf(ra[1].y); q0.u[6]=f2bf(ra[1].z); q0.u[7]=f2bf(ra[1].w); \
        q1.u[0]=f2bf(ra[2].x); q1.u[1]=f2bf(ra[2].y); q1.u[2]=f2bf(ra[2].z); q1.u[3]=f2bf(ra[2].w); \
        q1.u[4]=f2bf(ra[3].x); q1.u[5]=f2bf(ra[3].y); q1.u[6]=f2bf(ra[3].z); q1.u[7]=f2bf(ra[3].w); \
        q2.u[0]=f2bf(rb[0].x); q2.u[1]=f2bf(rb[0].y); q2.u[2]=f2bf(rb[0].z); q2.u[3]=f2bf(rb[0].w); \
        q2.u[4]=f2bf(rb[1].x); q2.u[5]=f2bf(rb[1].y); q2.u[6]=f2bf(rb[1].z); q2.u[7]=f2bf(rb[1].w); \
        q3.u[0]=f2bf(rb[2].x); q3.u[1]=f2bf(rb[2].y); q3.u[2]=f2bf(rb[2].z); q3.u[3]=f2bf(rb[2].w); \
        q3.u[4]=f2bf(rb[3].x); q3.u[5]=f2bf(rb[3].y); q3.u[6]=f2bf(rb[3].z); q3.u[7]=f2bf(rb[3].w); \
        *(int4*)(lw + (buf) * 16384 + wb00) = q0.v;                      \
        *(int4*)(lw + (buf) * 16384 + wb01) = q1.v;                      \
        *(int4*)(lw + (buf) * 16384 + wb10) = q2.v;                      \
        *(int4*)(lw + (buf) * 16384 + wb11) = q3.v;                      \
    }
#define STAGEB(buf, k0)                                                  \
    {                                                                    \
        _Pragma("unroll") for (int q = 0; q < 4; ++q)                    \
            gload16(srcB[q] + (k0), (char*)&Bs[buf][0] + pq[q]);         \
    }

    LOADA(0);
    STAGEB(0, 0);
    CVTWRITE(0);
    __syncthreads();

    int cur = 0;
    for (int t = 0; t < 8; ++t) {
        if (t < 7) {
            LOADA((t + 1) * 64);
            STAGEB(cur ^ 1, (t + 1) * 64);
        }
#pragma unroll
        for (int kk = 0; kk < 2; ++kk) {
            bf16x8 af[4], bfr[4];
#pragma unroll
            for (int i = 0; i < 4; ++i) {
                const int off = (wm + i * 16 + lr) * 128 + ((kk * 64 + lkb) ^ sw);
                af[i] = *(const bf16x8*)((const char*)&As[cur][0] + off);
            }
#pragma unroll
            for (int j = 0; j < 4; ++j) {
                const int off = (wn + j * 16 + lr) * 128 + ((kk * 64 + lkb) ^ sw);
                bfr[j] = *(const bf16x8*)((const char*)&Bs[cur][0] + off);
            }
#pragma unroll
            for (int i = 0; i < 4; ++i)
#pragma unroll
                for (int j = 0; j < 4; ++j)
                    acc[i][j] = __builtin_amdgcn_mfma_f32_16x16x32_bf16(
                        af[i], bfr[j], acc[i][j], 0, 0, 0);
        }
        if (t < 7) CVTWRITE(cur ^ 1);
        __syncthreads();
        cur ^= 1;
    }
#undef LOADA
#undef CVTWRITE
#undef STAGEB

    float bv[4];
#pragma unroll
    for (int j = 0; j < 4; ++j) bv[j] = bias[bn + wn + j * 16 + lr];
    const int rq = (l >> 4) * 4;
#pragma unroll
    for (int i = 0; i < 4; ++i)
#pragma unroll
        for (int q = 0; q < 4; ++q) {
            const long row = brow + wm + i * 16 + rq + q;
            u16* crow = C + row * 512 + bn + wn + lr;
#pragma unroll
            for (int j = 0; j < 4; ++j)
                crow[j * 16] = f2bf(fmaxf(acc[i][j][q] + bv[j], 0.f));
        }
}

// ---------------------------------------------------------------------------
// gemm_pipe: counted-vmcnt 3-buffer depth-2 pipeline, RACE-FIXED.
// BM=64, BN=128, BK=64, grid 1024, 4 waves (1Mx4N), wave-tile 64x32.
// Region t:  STAGE((t+2)%3)  [top, after barrier — prev reads of that buffer
//            were drained by lgkmcnt(0) before that barrier]
//            ds_read buf t%3 + MFMA
//            lgkmcnt(0) (reads done) ; vmcnt(6) [my buf-(t+1) loads landed;
//            6 = one newer stage in flight; NEVER 0 mid-loop]
//            s_barrier  [publishes: ALL waves' buf-(t+1) loads landed]
// Cross-wave safe: every wave certifies its own DMA BEFORE the barrier.
// EPI 0: C bf16 write. EPI 1: fused relu+bias, dot with Wfc -> partials.
// ---------------------------------------------------------------------------
template <int EPI>
__global__ __launch_bounds__(256, 2) void gemm_pipe(const u16* __restrict__ A,
                                                    const u16* __restrict__ Bt,
                                                    const float* __restrict__ b2,
                                                    const float* __restrict__ Wfc,
                                                    u16* __restrict__ C,
                                                    float* __restrict__ partials) {
    __shared__ __attribute__((aligned(16))) u16 As[3][64 * 64];    // 8KB x3
    __shared__ __attribute__((aligned(16))) u16 Bs[3][128 * 64];   // 16KB x3

    const int tid = threadIdx.x;
    const int bid = blockIdx.x;
    const int swz = (bid & 7) * 128 + (bid >> 3);   // 1024 blocks, bijective
    const int  bn   = (swz & 3) * 128;
    const long brow = (long)(swz >> 2) * 64;

    const int w  = tid >> 6;        // 0..3
    const int l  = tid & 63;
    const int wn = w * 32;
    const int lr  = l & 15;
    const int lkb = (l >> 4) * 16;
    const int sw  = (lr & 7) << 4;

    int pa[2], pb[4];
    const u16* srcA[2];
    const u16* srcB[4];
#pragma unroll
    for (int q = 0; q < 2; ++q) {
        const int p   = tid * 16 + q * 4096;
        const int row = p >> 7;
        const int cb  = (p & 127) ^ ((row & 7) << 4);
        pa[q]   = p;
        srcA[q] = A + (brow + row) * 512 + (cb >> 1);
    }
#pragma unroll
    for (int q = 0; q < 4; ++q) {
        const int p   = tid * 16 + q * 4096;
        const int row = p >> 7;
        const int cb  = (p & 127) ^ ((row & 7) << 4);
        pb[q]   = p;
        srcB[q] = Bt + (long)(bn + row) * 512 + (cb >> 1);
    }

    f32x4 acc[4][2];
#pragma unroll
    for (int i = 0; i < 4; ++i)
#pragma unroll
        for (int j = 0; j < 2; ++j) {
            f32x4 z = {0.f, 0.f, 0.f, 0.f};
            acc[i][j] = z;
        }

#define STAGEP(buf, k0)                                                  \
    {                                                                    \
        gload16(srcA[0] + (k0), (char*)&As[buf][0] + pa[0]);             \
        gload16(srcA[1] + (k0), (char*)&As[buf][0] + pa[1]);             \
        gload16(srcB[0] + (k0), (char*)&Bs[buf][0] + pb[0]);             \
        gload16(srcB[1] + (k0), (char*)&Bs[buf][0] + pb[1]);             \
        gload16(srcB[2] + (k0), (char*)&Bs[buf][0] + pb[2]);             \
        gload16(srcB[3] + (k0), (char*)&Bs[buf][0] + pb[3]);             \
    }

    STAGEP(0, 0);
    STAGEP(1, 64);
    WAITV(6);                          // my buf0 loads landed
    __builtin_amdgcn_s_barrier();      // everyone's buf0 loads landed

#pragma unroll
    for (int t = 0; t < 8; ++t) {
        if (t < 6) {
            const int nb = (t + 2) % 3;
            if (nb == 0)      STAGEP(0, (t + 2) * 64)
            else if (nb == 1) STAGEP(1, (t + 2) * 64)
            else              STAGEP(2, (t + 2) * 64)
        }

        const int cb = t % 3;
        const char* ab = cb == 0 ? (const char*)&As[0][0]
                       : cb == 1 ? (const char*)&As[1][0] : (const char*)&As[2][0];
        const char* bb = cb == 0 ? (const char*)&Bs[0][0]
                       : cb == 1 ? (const char*)&Bs[1][0] : (const char*)&Bs[2][0];
#pragma unroll
        for (int kk = 0; kk < 2; ++kk) {
            bf16x8 af[4], bfr[2];
#pragma unroll
            for (int i = 0; i < 4; ++i) {
                const int off = (i * 16 + lr) * 128 + ((kk * 64 + lkb) ^ sw);
                af[i] = *(const bf16x8*)(ab + off);
            }
#pragma unroll
            for (int j = 0; j < 2; ++j) {
                const int off = (wn + j * 16 + lr) * 128 + ((kk * 64 + lkb) ^ sw);
                bfr[j] = *(const bf16x8*)(bb + off);
            }
#pragma unroll
            for (int i = 0; i < 4; ++i)
#pragma unroll
                for (int j = 0; j < 2; ++j)
                    acc[i][j] = __builtin_amdgcn_mfma_f32_16x16x32_bf16(
                        af[i], bfr[j], acc[i][j], 0, 0, 0);
        }

        if (t < 7) {
            WAITLG0();                           // my ds_reads of buf t done
            __builtin_amdgcn_sched_barrier(0);   // pin (anti-sink, rule #18)
            if (t < 6) WAITV(6);                 // my buf-(t+1) DMA landed
            else       WAITV(0);                 // t==6: drain last stage
            __builtin_amdgcn_s_barrier();        // publish to all waves
        }
    }
#undef STAGEP

    const int rq = (l >> 4) * 4;
    if (EPI == 0) {
#pragma unroll
        for (int i = 0; i < 4; ++i)
#pragma unroll
            for (int q = 0; q < 4; ++q) {
                const long row = brow + i * 16 + rq + q;
                u16* crow = C + row * 512 + bn + wn + lr;
#pragma unroll
                for (int j = 0; j < 2; ++j)
                    crow[j * 16] = f2bf(acc[i][j][q]);
            }
    } else {
        float bvv[2], w0v[2], w1v[2];
#pragma unroll
        for (int j = 0; j < 2; ++j) {
            const int col = bn + wn + j * 16 + lr;
            bvv[j] = b2[col];
            w0v[j] = Wfc[2 * col];
            w1v[j] = Wfc[2 * col + 1];
        }
        const int slot = (bn >> 7) * 4 + w;   // 0..15
#pragma unroll
        for (int i = 0; i < 4; ++i)
#pragma unroll
            for (int q = 0; q < 4; ++q) {
                float s0 = 0.f, s1 = 0.f;
#pragma unroll
                for (int j = 0; j < 2; ++j) {
                    const float v = fmaxf(acc[i][j][q] + bvv[j], 0.f);
                    s0 += v * w0v[j];
                    s1 += v * w1v[j];
                }
#pragma unroll
                for (int m = 1; m < 16; m <<= 1) {
                    s0 += __shfl_xor(s0, m);
                    s1 += __shfl_xor(s1, m);
                }
                if (lr == 0) {
                    const long row = brow + i * 16 + rq + q;
                    float* pp = partials + ((long)slot * M_ + row) * 2;
                    pp[0] = s0;
                    pp[1] = s1;
                }
            }
    }
}

// ---------------------------------------------------------------------------
// aw = winsum11(g): bf16 in -> bf16 (for gemm4) AND f32 (final output 2)
// ---------------------------------------------------------------------------
__global__ __launch_bounds__(256) void winsum_f(const u16* __restrict__ g,
                                                u16* __restrict__ awb,
                                                float* __restrict__ awf) {
    const long idx = (long)blockIdx.x * 256 + threadIdx.x;
    const int  c8  = (int)(idx & 63);
    const long bs  = idx >> 6;
    const int  s   = (int)(bs & (S_ - 1));

    float acc[8] = {};
#pragma unroll
    for (int d = -AW_; d <= AW_; ++d) {
        const int ss = s + d;
        if (0 <= ss && ss < S_) {
            const int4 v = *(const int4*)&g[(bs + d) * HID_ + c8 * 8];
            const u16* u = (const u16*)&v;
#pragma unroll
            for (int e = 0; e < 8; ++e) acc[e] += bf2f(u[e]);
        }
    }
    union { u16 u[8]; int4 v; } r;
#pragma unroll
    for (int e = 0; e < 8; ++e) r.u[e] = f2bf(acc[e]);
    *(int4*)&awb[bs * HID_ + c8 * 8] = r.v;
    float4 o0 = {acc[0], acc[1], acc[2], acc[3]};
    float4 o1 = {acc[4], acc[5], acc[6], acc[7]};
    *(float4*)&awf[bs * HID_ + c8 * 8]     = o0;
    *(float4*)&awf[bs * HID_ + c8 * 8 + 4] = o1;
}

// ---------------------------------------------------------------------------
// out[row] = sum_16 partials + bfc
// ---------------------------------------------------------------------------
__global__ __launch_bounds__(256) void fc_reduce(const float* __restrict__ partials,
                                                 const float* __restrict__ bfc,
                                                 float* __restrict__ out) {
    const int row = blockIdx.x * 256 + threadIdx.x;
    float s0 = bfc[0], s1 = bfc[1];
#pragma unroll
    for (int p = 0; p < 16; ++p) {
        s0 += partials[((long)p * M_ + row) * 2 + 0];
        s1 += partials[((long)p * M_ + row) * 2 + 1];
    }
    out[row * 2 + 0] = s0;
    out[row * 2 + 1] = s1;
}

// ---------------------------------------------------------------------------
extern "C" void kernel_launch(void* const* d_in, const int* in_sizes, int n_in,
                              void* d_out, int out_size, void* d_ws, size_t ws_size,
                              hipStream_t stream) {
    const float* x   = (const float*)d_in[0];
    const float* W1  = (const float*)d_in[1];
    const float* b1  = (const float*)d_in[2];
    // d_in[3]=Wq, d_in[4]=Wk dead: softmax over singleton axis == 1.0
    const float* Wv  = (const float*)d_in[5];
    const float* W2  = (const float*)d_in[6];
    const float* b2  = (const float*)d_in[7];
    const float* Wfc = (const float*)d_in[8];
    const float* bfc = (const float*)d_in[9];

    float* out_part = (float*)d_out;                 // 16384*2 f32
    float* aw_f32   = (float*)d_out + (long)M_ * 2;  // 16384*512 f32 (32MB) "Q"

    unsigned char* ws = (unsigned char*)d_ws;

    // Q doubles as scratch until winsum_f overwrites it with the f32 aw:
    u16* W1t = (u16*)aw_f32;            // 512KB, dead after gemm1
    u16* Wvt = W1t + 262144;            // 512KB, dead after gemm3

    // ws layout (proven >= 32MB; fills indicate ~256MB):
    u16* h   = (u16*)ws;                           // [0,16M):  h, then awb
    u16* g   = (u16*)ws + 8388608;                 // [16M,32M): g (dead after winsum)
    u16* awb = h;
    float* partials = (float*)(ws + (17l << 20));  // 2MB @ [17M,19M) (in dead g)

    const bool big = ws_size >= ((size_t)34 << 20);
    u16* W2t = big ? (u16*)(ws + (33l << 20)) : g; // fallback: g-region, late

    // 1) weight prep (+W2 if big ws)
    prep_w<<<768, 256, 0, stream>>>(W1, Wv, W2, W1t, Wvt, W2t, big ? 1 : 0);
    // 2) h = relu(x @ W1 + b1)   (f32->bf16 cvt fused)
    gemm1_f32a<<<512, 256, 0, stream>>>(x, W1t, b1, h);
    // 3) g = h @ Wv              (winsum commutes with Wv)
    gemm_pipe<0><<<1024, 256, 0, stream>>>(h, Wvt, nullptr, nullptr, g, nullptr);
    // 4) aw = winsum11(g) -> bf16 (ws) + f32 (output 2, fills Q)
    winsum_f<<<4096, 256, 0, stream>>>(g, awb, aw_f32);
    // 5) fallback: W2^T late, into dead g region
    if (!big)
        trans_w2<<<dim3(16, 16), 256, 0, stream>>>(W2, W2t);
    // 6) partial out = relu(aw @ W2 + b2) @ Wfc   (t never materialized)
    gemm_pipe<1><<<1024, 256, 0, stream>>>(awb, W2t, b2, Wfc, nullptr, partials);
    // 7) out = sum partials + bfc
    fc_reduce<<<64, 256, 0, stream>>>(partials, bfc, out_part);
}